// Round 7
// baseline (54.647 us; speedup 1.0000x reference)
//
#include <hip/hip_runtime.h>

namespace {
constexpr int kB = 32, kT = 30, kD = 512, kL = 196;
constexpr float kK = 2.8853900817779268f;  // 2*log2(e)
constexpr size_t kEgN = (size_t)kB * kT * kD;           // 491,520
constexpr size_t kFN = (size_t)kB * 128 * kL * 4;       // 3,211,264
constexpr size_t kGsz = (size_t)kB * kT * kL;           // 188,160

// Eg[b][t][d] = 2^(kK*(x+w))
__global__ __launch_bounds__(256) void k_prep_e(const float* __restrict__ x,
                                                const float* __restrict__ w,
                                                float* __restrict__ Eg) {
  const float4* x4 = (const float4*)x;
  const float4* w4 = (const float4*)w;
  float4* e4 = (float4*)Eg;
  const int n4 = (int)(kEgN / 4);
  for (int i = blockIdx.x * 256 + threadIdx.x; i < n4; i += gridDim.x * 256) {
    const float4 a = x4[i], b = w4[i];
    float4 r;
    r.x = __builtin_amdgcn_exp2f(kK * (a.x + b.x));
    r.y = __builtin_amdgcn_exp2f(kK * (a.y + b.y));
    r.z = __builtin_amdgcn_exp2f(kK * (a.z + b.z));
    r.w = __builtin_amdgcn_exp2f(kK * (a.w + b.w));
    e4[i] = r;
  }
}

// imgF4[b][dq][l][j] = 2^(kK*img[b][l][4*dq+j]); dq in [0,128)
__global__ __launch_bounds__(256) void k_prep_f(const float* __restrict__ img,
                                                float* __restrict__ imgF4) {
  const int lq = blockIdx.x, b = blockIdx.y;
  const int tid = threadIdx.x;
  const int ls = tid >> 7, dq = tid & 127;
#pragma unroll
  for (int r = 0; r < 7; ++r) {
    const int l = lq * 14 + 2 * r + ls;
    const float4 v = *(const float4*)(img + ((size_t)(b * kL + l)) * kD + 4 * dq);
    float4 o;
    o.x = __builtin_amdgcn_exp2f(kK * v.x);
    o.y = __builtin_amdgcn_exp2f(kK * v.y);
    o.z = __builtin_amdgcn_exp2f(kK * v.z);
    o.w = __builtin_amdgcn_exp2f(kK * v.w);
    *(float4*)(imgF4 + (((size_t)(b * 128 + dq)) * kL + l) * 4) = o;
  }
}

// g2[dh][b][t][l] (l<192) = sum over 256 d of vw_d/(1+E*F).
// Flat grid 1536, XCD b-affinity swizzle: bgroup = n&7.
// Wave = (b, lc:3, tq:8, dh:2); lane = l. E/vw wave-uniform -> scalar loads.
__global__ __launch_bounds__(64) void k_scoreT(const float* __restrict__ Eg,
                                               const float* __restrict__ imgF4,
                                               const float* __restrict__ vw,
                                               float* __restrict__ g2) {
  const int lane = threadIdx.x;
  int n = blockIdx.x;
  const int bg = n & 7;
  int m = n >> 3;             // 192 = 4(bi) * 3(lc) * 8(tq) * 2(dh)
  const int bi = m & 3; m >>= 2;
  const int lc = m % 3; m /= 3;
  const int tq = m & 7;
  const int dh = m >> 3;
  const int b = bg * 4 + bi;
  const int l0 = lc * 64;
  const int t0 = tq * 4;
  const int tc0 = t0, tc1 = t0 + 1;
  const int tc2 = (t0 + 2 < kT) ? t0 + 2 : kT - 1;
  const int tc3 = (t0 + 3 < kT) ? t0 + 3 : kT - 1;
  const float* Fp = imgF4 + (((size_t)(b * 128 + dh * 64)) * kL + l0 + lane) * 4;
  const float* e0 = Eg + ((size_t)(b * kT + tc0)) * kD + dh * 256;
  const float* e1 = Eg + ((size_t)(b * kT + tc1)) * kD + dh * 256;
  const float* e2 = Eg + ((size_t)(b * kT + tc2)) * kD + dh * 256;
  const float* e3 = Eg + ((size_t)(b * kT + tc3)) * kD + dh * 256;
  const float* vp = vw + dh * 256;
  float a0 = 0.f, a1 = 0.f, a2 = 0.f, a3 = 0.f;
#pragma unroll 2
  for (int s = 0; s < 64; ++s) {
    const float4 f = *(const float4*)(Fp + (size_t)s * (kL * 4));
    const float4 vv = *(const float4*)(vp + 4 * s);      // uniform
    // vv.x/u + vv.y/v = (vv.x*v + vv.y*u) * rcp(u*v)
    {
      const float4 e = *(const float4*)(e0 + 4 * s);     // uniform
      float u = fmaf(e.x, f.x, 1.f), v = fmaf(e.y, f.y, 1.f);
      a0 = fmaf(fmaf(v, vv.x, u * vv.y), __builtin_amdgcn_rcpf(u * v), a0);
      u = fmaf(e.z, f.z, 1.f); v = fmaf(e.w, f.w, 1.f);
      a0 = fmaf(fmaf(v, vv.z, u * vv.w), __builtin_amdgcn_rcpf(u * v), a0);
    }
    {
      const float4 e = *(const float4*)(e1 + 4 * s);
      float u = fmaf(e.x, f.x, 1.f), v = fmaf(e.y, f.y, 1.f);
      a1 = fmaf(fmaf(v, vv.x, u * vv.y), __builtin_amdgcn_rcpf(u * v), a1);
      u = fmaf(e.z, f.z, 1.f); v = fmaf(e.w, f.w, 1.f);
      a1 = fmaf(fmaf(v, vv.z, u * vv.w), __builtin_amdgcn_rcpf(u * v), a1);
    }
    {
      const float4 e = *(const float4*)(e2 + 4 * s);
      float u = fmaf(e.x, f.x, 1.f), v = fmaf(e.y, f.y, 1.f);
      a2 = fmaf(fmaf(v, vv.x, u * vv.y), __builtin_amdgcn_rcpf(u * v), a2);
      u = fmaf(e.z, f.z, 1.f); v = fmaf(e.w, f.w, 1.f);
      a2 = fmaf(fmaf(v, vv.z, u * vv.w), __builtin_amdgcn_rcpf(u * v), a2);
    }
    {
      const float4 e = *(const float4*)(e3 + 4 * s);
      float u = fmaf(e.x, f.x, 1.f), v = fmaf(e.y, f.y, 1.f);
      a3 = fmaf(fmaf(v, vv.x, u * vv.y), __builtin_amdgcn_rcpf(u * v), a3);
      u = fmaf(e.z, f.z, 1.f); v = fmaf(e.w, f.w, 1.f);
      a3 = fmaf(fmaf(v, vv.z, u * vv.w), __builtin_amdgcn_rcpf(u * v), a3);
    }
  }
  float* gp = g2 + (size_t)dh * kGsz + ((size_t)(b * kT)) * kL + l0 + lane;
  gp[(size_t)t0 * kL] = a0;
  gp[(size_t)(t0 + 1) * kL] = a1;
  if (t0 + 2 < kT) gp[(size_t)(t0 + 2) * kL] = a2;
  if (t0 + 3 < kT) gp[(size_t)(t0 + 3) * kL] = a3;
}

// softmax over l: l<192 from g2 halves; l=192..195 computed inline (all 512 d)
__global__ __launch_bounds__(512) void k_alpha(const float* __restrict__ g2,
                                               const float* __restrict__ Eg,
                                               const float* __restrict__ img,
                                               const float* __restrict__ vw,
                                               float* __restrict__ alpha) {
  const int qd = blockIdx.x, b = blockIdx.y;
  const int lane = threadIdx.x & 63, wv = threadIdx.x >> 6;
  const int t = qd * 8 + wv;
  if (t >= kT) return;
  // tail: lane = (l4:4, dc:16); each lane sums 32 d for l = 192+l4
  const int l4 = lane & 3, dc = lane >> 2;
  const float* ir = img + ((size_t)(b * kL + 192 + l4)) * kD + dc * 32;
  const float* er = Eg + ((size_t)(b * kT + t)) * kD + dc * 32;
  const float* vr = vw + dc * 32;
  float tg = 0.f;
#pragma unroll
  for (int k = 0; k < 8; ++k) {
    const float4 iv = *(const float4*)(ir + 4 * k);
    const float4 ev = *(const float4*)(er + 4 * k);
    const float4 vv = *(const float4*)(vr + 4 * k);
    float u = fmaf(ev.x, __builtin_amdgcn_exp2f(kK * iv.x), 1.f);
    float v = fmaf(ev.y, __builtin_amdgcn_exp2f(kK * iv.y), 1.f);
    tg = fmaf(fmaf(v, vv.x, u * vv.y), __builtin_amdgcn_rcpf(u * v), tg);
    u = fmaf(ev.z, __builtin_amdgcn_exp2f(kK * iv.z), 1.f);
    v = fmaf(ev.w, __builtin_amdgcn_exp2f(kK * iv.w), 1.f);
    tg = fmaf(fmaf(v, vv.z, u * vv.w), __builtin_amdgcn_rcpf(u * v), tg);
  }
#pragma unroll
  for (int mm = 4; mm < 64; mm <<= 1) tg += __shfl_xor(tg, mm, 64);
  // lane L now holds tail-sum for l = 192+(L&3)
  const size_t base = ((size_t)(b * kT + t)) * kL;
  const float* g0 = g2 + base;
  const float* g1 = g2 + kGsz + base;
  float q0 = (g0[lane] + g1[lane]) * kK;
  float q1 = (g0[lane + 64] + g1[lane + 64]) * kK;
  float q2 = (g0[lane + 128] + g1[lane + 128]) * kK;
  float q3 = (lane < 4) ? tg * kK : __builtin_inff();
  float m = fminf(fminf(q0, q1), fminf(q2, q3));
#pragma unroll
  for (int mm = 1; mm < 64; mm <<= 1) m = fminf(m, __shfl_xor(m, mm, 64));
  const float e0 = __builtin_amdgcn_exp2f(m - q0);
  const float e1 = __builtin_amdgcn_exp2f(m - q1);
  const float e2 = __builtin_amdgcn_exp2f(m - q2);
  const float e3 = (lane < 4) ? __builtin_amdgcn_exp2f(m - q3) : 0.f;
  float s = e0 + e1 + e2 + e3;
#pragma unroll
  for (int mm = 1; mm < 64; mm <<= 1) s += __shfl_xor(s, mm, 64);
  const float rs = __builtin_amdgcn_rcpf(s);
  float* ab = alpha + base;
  ab[lane] = e0 * rs;
  ab[lane + 64] = e1 * rs;
  ab[lane + 128] = e2 * rs;
  if (lane < 4) ab[lane + 192] = e3 * rs;
}

// context[b][t][d] = sum_l img[b][l][d]*alpha[b][t][l].
// Flat grid 384, XCD b-affinity swizzle. 4 waves own 49-l quarters.
__global__ __launch_bounds__(256) void k_ctx(const float* __restrict__ img,
                                             const float* __restrict__ alpha,
                                             float* __restrict__ out) {
  __shared__ __align__(16) float red[4][5][256];  // 20 KB
  int n = blockIdx.x;
  const int bg = n & 7;
  int m = n >> 3;  // 48 = 4(bi) * 6(tg) * 2(dh)
  const int bi = m & 3; m >>= 2;
  const int tg = m % 6;
  const int dh = m / 6;
  const int b = bg * 4 + bi;
  const int t0 = tg * 5, d0 = dh * 256;
  const int tid = threadIdx.x;
  const int lane = tid & 63;
  const int lru = __builtin_amdgcn_readfirstlane(tid >> 6);
  const float* ap = alpha + ((size_t)(b * kT + t0)) * kL + lru * 49;  // uniform
  const float* ip = img + ((size_t)(b * kL + lru * 49)) * kD + d0 + 4 * lane;
  float4 acc[5];
#pragma unroll
  for (int j = 0; j < 5; ++j) acc[j] = {0.f, 0.f, 0.f, 0.f};
#pragma unroll 4
  for (int i = 0; i < 49; ++i) {
    const float4 v = *(const float4*)(ip + (size_t)i * kD);
    const float a0 = ap[i];
    const float a1 = ap[kL + i];
    const float a2 = ap[2 * kL + i];
    const float a3 = ap[3 * kL + i];
    const float a4 = ap[4 * kL + i];
    acc[0].x = fmaf(v.x, a0, acc[0].x); acc[0].y = fmaf(v.y, a0, acc[0].y);
    acc[0].z = fmaf(v.z, a0, acc[0].z); acc[0].w = fmaf(v.w, a0, acc[0].w);
    acc[1].x = fmaf(v.x, a1, acc[1].x); acc[1].y = fmaf(v.y, a1, acc[1].y);
    acc[1].z = fmaf(v.z, a1, acc[1].z); acc[1].w = fmaf(v.w, a1, acc[1].w);
    acc[2].x = fmaf(v.x, a2, acc[2].x); acc[2].y = fmaf(v.y, a2, acc[2].y);
    acc[2].z = fmaf(v.z, a2, acc[2].z); acc[2].w = fmaf(v.w, a2, acc[2].w);
    acc[3].x = fmaf(v.x, a3, acc[3].x); acc[3].y = fmaf(v.y, a3, acc[3].y);
    acc[3].z = fmaf(v.z, a3, acc[3].z); acc[3].w = fmaf(v.w, a3, acc[3].w);
    acc[4].x = fmaf(v.x, a4, acc[4].x); acc[4].y = fmaf(v.y, a4, acc[4].y);
    acc[4].z = fmaf(v.z, a4, acc[4].z); acc[4].w = fmaf(v.w, a4, acc[4].w);
  }
#pragma unroll
  for (int j = 0; j < 5; ++j) *(float4*)&red[lru][j][4 * lane] = acc[j];
  __syncthreads();
#pragma unroll
  for (int j = 0; j < 5; ++j) {
    const float s =
        red[0][j][tid] + red[1][j][tid] + red[2][j][tid] + red[3][j][tid];
    out[((size_t)(b * kT + t0 + j)) * kD + d0 + tid] = s;
  }
}
}  // namespace

extern "C" void kernel_launch(void* const* d_in, const int* in_sizes, int n_in,
                              void* d_out, int out_size, void* d_ws, size_t ws_size,
                              hipStream_t stream) {
  const float* x = (const float*)d_in[0];
  const float* wordemb = (const float*)d_in[1];
  const float* img = (const float*)d_in[2];
  const float* vw = (const float*)d_in[3];
  // v_b (d_in[4]) cancels in the softmax along with sum(v_w) — unused by design.
  float* out = (float*)d_out;
  float* Eg = (float*)d_ws;        // 1.97 MB
  float* imgF4 = Eg + kEgN;        // 12.8 MB
  float* g2 = imgF4 + kFN;         // 1.51 MB
  float* alpha = g2 + 2 * kGsz;    // 0.75 MB
  hipLaunchKernelGGL(k_prep_e, dim3(240), dim3(256), 0, stream, x, wordemb, Eg);
  hipLaunchKernelGGL(k_prep_f, dim3(14, kB), dim3(256), 0, stream, img, imgF4);
  hipLaunchKernelGGL(k_scoreT, dim3(1536), dim3(64), 0, stream, Eg, imgF4, vw,
                     g2);
  hipLaunchKernelGGL(k_alpha, dim3(4, kB), dim3(512), 0, stream, g2, Eg, img,
                     vw, alpha);
  hipLaunchKernelGGL(k_ctx, dim3(384), dim3(256), 0, stream, img, alpha, out);
}

// Round 8
// 41.702 us; speedup vs baseline: 1.3104x; 1.3104x over previous
//
#include <hip/hip_runtime.h>

namespace {
constexpr int kB = 32, kT = 30, kD = 512, kL = 196;
constexpr float kK = 2.8853900817779268f;  // 2*log2(e)
constexpr size_t kEgN = (size_t)kB * kT * kD;      // 491,520
constexpr size_t kFN = (size_t)kB * 128 * kL * 4;  // 3,211,264
constexpr size_t kGsz = (size_t)kB * kT * kL;      // 188,160

// Fused prep: blocks [0,120) -> Eg = 2^(kK(x+w)); [120,568) -> imgF4 transpose-exp.
__global__ __launch_bounds__(256) void k_prep(const float* __restrict__ x,
                                              const float* __restrict__ w,
                                              const float* __restrict__ img,
                                              float* __restrict__ Eg,
                                              float* __restrict__ imgF4) {
  const int bx = blockIdx.x;
  if (bx < 120) {
    const float4* x4 = (const float4*)x;
    const float4* w4 = (const float4*)w;
    float4* e4 = (float4*)Eg;
#pragma unroll
    for (int k = 0; k < 4; ++k) {
      const int i = bx * 256 + threadIdx.x + k * 120 * 256;
      const float4 a = x4[i], b = w4[i];
      float4 r;
      r.x = __builtin_amdgcn_exp2f(kK * (a.x + b.x));
      r.y = __builtin_amdgcn_exp2f(kK * (a.y + b.y));
      r.z = __builtin_amdgcn_exp2f(kK * (a.z + b.z));
      r.w = __builtin_amdgcn_exp2f(kK * (a.w + b.w));
      e4[i] = r;
    }
  } else {
    const int n = bx - 120;  // 448 = 14 lq x 32 b
    const int lq = n % 14, b = n / 14;
    const int tid = threadIdx.x;
    const int ls = tid >> 7, dq = tid & 127;
#pragma unroll
    for (int r = 0; r < 7; ++r) {
      const int l = lq * 14 + 2 * r + ls;
      const float4 v =
          *(const float4*)(img + ((size_t)(b * kL + l)) * kD + 4 * dq);
      float4 o;
      o.x = __builtin_amdgcn_exp2f(kK * v.x);
      o.y = __builtin_amdgcn_exp2f(kK * v.y);
      o.z = __builtin_amdgcn_exp2f(kK * v.z);
      o.w = __builtin_amdgcn_exp2f(kK * v.w);
      *(float4*)(imgF4 + (((size_t)(b * 128 + dq)) * kL + l) * 4) = o;
    }
  }
}

// g4[dq][b][t][l] (l<192) = sum over 128 d of vw_d/(1+E*F).
// 5760 one-wave blocks; XCD b-affinity (bg = n&7 under round-robin dispatch).
// Double-buffered 8-deep F prefetch; E/vw wave-uniform -> scalar loads.
__global__ __launch_bounds__(64) void k_scoreT(const float* __restrict__ Eg,
                                               const float* __restrict__ imgF4,
                                               const float* __restrict__ vw,
                                               float* __restrict__ g4) {
  const int lane = threadIdx.x;
  int n = blockIdx.x;
  const int bg = n & 7;
  int m = n >> 3;             // 720 = 4 bi * 3 lc * 15 tp * 4 dq
  const int bi = m & 3; m >>= 2;
  const int lc = m % 3; m /= 3;
  const int tp = m % 15;
  const int dq = m / 15;
  const int b = bg * 4 + bi;
  const int t0 = 2 * tp;
  const float* Fp =
      imgF4 + (((size_t)(b * 128 + dq * 32)) * kL + lc * 64 + lane) * 4;
  const float* e0 = Eg + ((size_t)(b * kT + t0)) * kD + dq * 128;
  const float* e1 = e0 + kD;
  const float* vp = vw + dq * 128;
  float a0 = 0.f, a1 = 0.f;
  auto loadF = [&](float4* dst, int bb) {
#pragma unroll
    for (int j = 0; j < 8; ++j)
      dst[j] = *(const float4*)(Fp + (size_t)(bb * 8 + j) * (kL * 4));
  };
  auto compF = [&](const float4* f, int bb) {
#pragma unroll
    for (int j = 0; j < 8; ++j) {
      const int s = bb * 8 + j;
      const float4 ev0 = *(const float4*)(e0 + 4 * s);  // uniform -> s_load
      const float4 ev1 = *(const float4*)(e1 + 4 * s);  // uniform -> s_load
      const float4 vv = *(const float4*)(vp + 4 * s);   // uniform -> s_load
      // vv.x/u + vv.y/v = (vv.x*v + vv.y*u) * rcp(u*v)
      float u = fmaf(ev0.x, f[j].x, 1.f), v = fmaf(ev0.y, f[j].y, 1.f);
      a0 = fmaf(fmaf(v, vv.x, u * vv.y), __builtin_amdgcn_rcpf(u * v), a0);
      u = fmaf(ev0.z, f[j].z, 1.f); v = fmaf(ev0.w, f[j].w, 1.f);
      a0 = fmaf(fmaf(v, vv.z, u * vv.w), __builtin_amdgcn_rcpf(u * v), a0);
      u = fmaf(ev1.x, f[j].x, 1.f); v = fmaf(ev1.y, f[j].y, 1.f);
      a1 = fmaf(fmaf(v, vv.x, u * vv.y), __builtin_amdgcn_rcpf(u * v), a1);
      u = fmaf(ev1.z, f[j].z, 1.f); v = fmaf(ev1.w, f[j].w, 1.f);
      a1 = fmaf(fmaf(v, vv.z, u * vv.w), __builtin_amdgcn_rcpf(u * v), a1);
    }
  };
  float4 fA[8], fB[8];
  loadF(fA, 0);
  loadF(fB, 1); compF(fA, 0);
  loadF(fA, 2); compF(fB, 1);
  loadF(fB, 3); compF(fA, 2);
  compF(fB, 3);
  float* gp = g4 + (size_t)dq * kGsz + ((size_t)(b * kT + t0)) * kL +
              lc * 64 + lane;
  gp[0] = a0;
  gp[kL] = a1;
}

// softmax over l: l<192 from 4 partials; l=192..195 computed inline (512 d)
__global__ __launch_bounds__(512) void k_alpha(const float* __restrict__ g4,
                                               const float* __restrict__ Eg,
                                               const float* __restrict__ img,
                                               const float* __restrict__ vw,
                                               float* __restrict__ alpha) {
  const int qd = blockIdx.x, b = blockIdx.y;
  const int lane = threadIdx.x & 63, wv = threadIdx.x >> 6;
  const int t = qd * 8 + wv;
  if (t >= kT) return;
  // tail: lane = (l4:4, dc:16); each lane sums 32 d for l = 192+l4
  const int l4 = lane & 3, dc = lane >> 2;
  const float* ir = img + ((size_t)(b * kL + 192 + l4)) * kD + dc * 32;
  const float* er = Eg + ((size_t)(b * kT + t)) * kD + dc * 32;
  const float* vr = vw + dc * 32;
  float tg = 0.f;
#pragma unroll
  for (int k = 0; k < 8; ++k) {
    const float4 iv = *(const float4*)(ir + 4 * k);
    const float4 ev = *(const float4*)(er + 4 * k);
    const float4 vv = *(const float4*)(vr + 4 * k);
    float u = fmaf(ev.x, __builtin_amdgcn_exp2f(kK * iv.x), 1.f);
    float v = fmaf(ev.y, __builtin_amdgcn_exp2f(kK * iv.y), 1.f);
    tg = fmaf(fmaf(v, vv.x, u * vv.y), __builtin_amdgcn_rcpf(u * v), tg);
    u = fmaf(ev.z, __builtin_amdgcn_exp2f(kK * iv.z), 1.f);
    v = fmaf(ev.w, __builtin_amdgcn_exp2f(kK * iv.w), 1.f);
    tg = fmaf(fmaf(v, vv.z, u * vv.w), __builtin_amdgcn_rcpf(u * v), tg);
  }
#pragma unroll
  for (int mm = 4; mm < 64; mm <<= 1) tg += __shfl_xor(tg, mm, 64);
  const size_t base = ((size_t)(b * kT + t)) * kL;
  const float* p0 = g4 + base;
  const float* p1 = g4 + kGsz + base;
  const float* p2 = g4 + 2 * kGsz + base;
  const float* p3 = g4 + 3 * kGsz + base;
  float q0 = (p0[lane] + p1[lane] + p2[lane] + p3[lane]) * kK;
  float q1 = (p0[lane + 64] + p1[lane + 64] + p2[lane + 64] + p3[lane + 64]) * kK;
  float q2 = (p0[lane + 128] + p1[lane + 128] + p2[lane + 128] + p3[lane + 128]) * kK;
  float q3 = (lane < 4) ? tg * kK : __builtin_inff();
  float m = fminf(fminf(q0, q1), fminf(q2, q3));
#pragma unroll
  for (int mm = 1; mm < 64; mm <<= 1) m = fminf(m, __shfl_xor(m, mm, 64));
  const float e0 = __builtin_amdgcn_exp2f(m - q0);
  const float e1 = __builtin_amdgcn_exp2f(m - q1);
  const float e2 = __builtin_amdgcn_exp2f(m - q2);
  const float e3 = (lane < 4) ? __builtin_amdgcn_exp2f(m - q3) : 0.f;
  float s = e0 + e1 + e2 + e3;
#pragma unroll
  for (int mm = 1; mm < 64; mm <<= 1) s += __shfl_xor(s, mm, 64);
  const float rs = __builtin_amdgcn_rcpf(s);
  float* ab = alpha + base;
  ab[lane] = e0 * rs;
  ab[lane + 64] = e1 * rs;
  ab[lane + 128] = e2 * rs;
  if (lane < 4) ab[lane + 192] = e3 * rs;
}

// context[b][t][d] = sum_l img[b][l][d]*alpha[b][t][l].
// 384 blocks, XCD b-affinity; 4 waves own 49-l quarters; 8-deep img dbuf.
__global__ __launch_bounds__(256) void k_ctx(const float* __restrict__ img,
                                             const float* __restrict__ alpha,
                                             float* __restrict__ out) {
  __shared__ __align__(16) float red[4][5][256];  // 20 KB
  int n = blockIdx.x;
  const int bg = n & 7;
  int m = n >> 3;  // 48 = 4 bi * 6 tg * 2 dh
  const int bi = m & 3; m >>= 2;
  const int tg = m % 6;
  const int dh = m / 6;
  const int b = bg * 4 + bi;
  const int t0 = tg * 5, d0 = dh * 256;
  const int tid = threadIdx.x;
  const int lane = tid & 63;
  const int lru = __builtin_amdgcn_readfirstlane(tid >> 6);
  const float* ap = alpha + ((size_t)(b * kT + t0)) * kL + lru * 49;  // uniform
  const float* ip = img + ((size_t)(b * kL + lru * 49)) * kD + d0 + 4 * lane;
  float4 acc[5];
#pragma unroll
  for (int j = 0; j < 5; ++j) acc[j] = {0.f, 0.f, 0.f, 0.f};
  auto loadI = [&](float4* dst, int bb) {
#pragma unroll
    for (int j = 0; j < 8; ++j)
      dst[j] = *(const float4*)(ip + (size_t)(bb * 8 + j) * kD);
  };
  auto compI = [&](const float4* f, int bb) {
#pragma unroll
    for (int j = 0; j < 8; ++j) {
      const int i = bb * 8 + j;
      const float a0 = ap[i];
      const float a1 = ap[kL + i];
      const float a2 = ap[2 * kL + i];
      const float a3 = ap[3 * kL + i];
      const float a4 = ap[4 * kL + i];
      acc[0].x = fmaf(f[j].x, a0, acc[0].x); acc[0].y = fmaf(f[j].y, a0, acc[0].y);
      acc[0].z = fmaf(f[j].z, a0, acc[0].z); acc[0].w = fmaf(f[j].w, a0, acc[0].w);
      acc[1].x = fmaf(f[j].x, a1, acc[1].x); acc[1].y = fmaf(f[j].y, a1, acc[1].y);
      acc[1].z = fmaf(f[j].z, a1, acc[1].z); acc[1].w = fmaf(f[j].w, a1, acc[1].w);
      acc[2].x = fmaf(f[j].x, a2, acc[2].x); acc[2].y = fmaf(f[j].y, a2, acc[2].y);
      acc[2].z = fmaf(f[j].z, a2, acc[2].z); acc[2].w = fmaf(f[j].w, a2, acc[2].w);
      acc[3].x = fmaf(f[j].x, a3, acc[3].x); acc[3].y = fmaf(f[j].y, a3, acc[3].y);
      acc[3].z = fmaf(f[j].z, a3, acc[3].z); acc[3].w = fmaf(f[j].w, a3, acc[3].w);
      acc[4].x = fmaf(f[j].x, a4, acc[4].x); acc[4].y = fmaf(f[j].y, a4, acc[4].y);
      acc[4].z = fmaf(f[j].z, a4, acc[4].z); acc[4].w = fmaf(f[j].w, a4, acc[4].w);
    }
  };
  float4 fA[8], fB[8];
  loadI(fA, 0);
  loadI(fB, 1); compI(fA, 0);
  loadI(fA, 2); compI(fB, 1);
  loadI(fB, 3); compI(fA, 2);
  loadI(fA, 4); compI(fB, 3);
  loadI(fB, 5); compI(fA, 4);
  compI(fB, 5);
  {  // tail l-index 48 of this quarter
    const float4 v = *(const float4*)(ip + (size_t)48 * kD);
    const int i = 48;
    const float a0 = ap[i], a1 = ap[kL + i], a2 = ap[2 * kL + i],
                a3 = ap[3 * kL + i], a4 = ap[4 * kL + i];
    acc[0].x = fmaf(v.x, a0, acc[0].x); acc[0].y = fmaf(v.y, a0, acc[0].y);
    acc[0].z = fmaf(v.z, a0, acc[0].z); acc[0].w = fmaf(v.w, a0, acc[0].w);
    acc[1].x = fmaf(v.x, a1, acc[1].x); acc[1].y = fmaf(v.y, a1, acc[1].y);
    acc[1].z = fmaf(v.z, a1, acc[1].z); acc[1].w = fmaf(v.w, a1, acc[1].w);
    acc[2].x = fmaf(v.x, a2, acc[2].x); acc[2].y = fmaf(v.y, a2, acc[2].y);
    acc[2].z = fmaf(v.z, a2, acc[2].z); acc[2].w = fmaf(v.w, a2, acc[2].w);
    acc[3].x = fmaf(v.x, a3, acc[3].x); acc[3].y = fmaf(v.y, a3, acc[3].y);
    acc[3].z = fmaf(v.z, a3, acc[3].z); acc[3].w = fmaf(v.w, a3, acc[3].w);
    acc[4].x = fmaf(v.x, a4, acc[4].x); acc[4].y = fmaf(v.y, a4, acc[4].y);
    acc[4].z = fmaf(v.z, a4, acc[4].z); acc[4].w = fmaf(v.w, a4, acc[4].w);
  }
#pragma unroll
  for (int j = 0; j < 5; ++j) *(float4*)&red[lru][j][4 * lane] = acc[j];
  __syncthreads();
#pragma unroll
  for (int j = 0; j < 5; ++j) {
    const float s =
        red[0][j][tid] + red[1][j][tid] + red[2][j][tid] + red[3][j][tid];
    out[((size_t)(b * kT + t0 + j)) * kD + d0 + tid] = s;
  }
}
}  // namespace

extern "C" void kernel_launch(void* const* d_in, const int* in_sizes, int n_in,
                              void* d_out, int out_size, void* d_ws, size_t ws_size,
                              hipStream_t stream) {
  const float* x = (const float*)d_in[0];
  const float* wordemb = (const float*)d_in[1];
  const float* img = (const float*)d_in[2];
  const float* vw = (const float*)d_in[3];
  // v_b (d_in[4]) cancels in the softmax along with sum(v_w) — unused by design.
  float* out = (float*)d_out;
  float* Eg = (float*)d_ws;        // 1.97 MB
  float* imgF4 = Eg + kEgN;        // 12.8 MB
  float* g4 = imgF4 + kFN;         // 3.01 MB
  float* alpha = g4 + 4 * kGsz;    // 0.75 MB
  hipLaunchKernelGGL(k_prep, dim3(568), dim3(256), 0, stream, x, wordemb, img,
                     Eg, imgF4);
  hipLaunchKernelGGL(k_scoreT, dim3(5760), dim3(64), 0, stream, Eg, imgF4, vw,
                     g4);
  hipLaunchKernelGGL(k_alpha, dim3(4, kB), dim3(512), 0, stream, g4, Eg, img,
                     vw, alpha);
  hipLaunchKernelGGL(k_ctx, dim3(384), dim3(256), 0, stream, img, alpha, out);
}

// Round 9
// 40.982 us; speedup vs baseline: 1.3335x; 1.0176x over previous
//
#include <hip/hip_runtime.h>

namespace {
constexpr int kB = 32, kT = 30, kD = 512, kL = 196;
constexpr float kK = 2.8853900817779268f;  // 2*log2(e)
constexpr size_t kEgN = (size_t)kB * kT * kD;      // 491,520
constexpr size_t kFN = (size_t)kB * 128 * kL * 4;  // 3,211,264
constexpr size_t kGsz = (size_t)kB * kT * kL;      // 188,160

// vwi/u + vwj/v = (vwi*v + vwj*u) * rcp(u*v): 1 rcp per 2 elements
#define PAIR(ex, ey, fx, fy, vx, vy, acc)                                  \
  {                                                                        \
    const float u_ = fmaf(ex, fx, 1.f);                                    \
    const float v_ = fmaf(ey, fy, 1.f);                                    \
    acc = fmaf(fmaf(v_, vx, u_ * vy), __builtin_amdgcn_rcpf(u_ * v_), acc); \
  }

// Fused prep: blocks [0,120) -> Eg = 2^(kK(x+w)); [120,568) -> imgF4 transpose-exp.
__global__ __launch_bounds__(256) void k_prep(const float* __restrict__ x,
                                              const float* __restrict__ w,
                                              const float* __restrict__ img,
                                              float* __restrict__ Eg,
                                              float* __restrict__ imgF4) {
  const int bx = blockIdx.x;
  if (bx < 120) {
    const float4* x4 = (const float4*)x;
    const float4* w4 = (const float4*)w;
    float4* e4 = (float4*)Eg;
#pragma unroll
    for (int k = 0; k < 4; ++k) {
      const int i = bx * 256 + threadIdx.x + k * 120 * 256;
      const float4 a = x4[i], b = w4[i];
      float4 r;
      r.x = __builtin_amdgcn_exp2f(kK * (a.x + b.x));
      r.y = __builtin_amdgcn_exp2f(kK * (a.y + b.y));
      r.z = __builtin_amdgcn_exp2f(kK * (a.z + b.z));
      r.w = __builtin_amdgcn_exp2f(kK * (a.w + b.w));
      e4[i] = r;
    }
  } else {
    const int n = bx - 120;  // 448 = 14 lq x 32 b
    const int lq = n % 14, b = n / 14;
    const int tid = threadIdx.x;
    const int ls = tid >> 7, dq = tid & 127;
#pragma unroll
    for (int r = 0; r < 7; ++r) {
      const int l = lq * 14 + 2 * r + ls;
      const float4 v =
          *(const float4*)(img + ((size_t)(b * kL + l)) * kD + 4 * dq);
      float4 o;
      o.x = __builtin_amdgcn_exp2f(kK * v.x);
      o.y = __builtin_amdgcn_exp2f(kK * v.y);
      o.z = __builtin_amdgcn_exp2f(kK * v.z);
      o.w = __builtin_amdgcn_exp2f(kK * v.w);
      *(float4*)(imgF4 + (((size_t)(b * 128 + dq)) * kL + l) * 4) = o;
    }
  }
}

// g8[dq][b][t][l] (l<192) = sum over 64 d of vw_d/(1+E*F).
// 6144 one-wave blocks (6 waves/SIMD); XCD b-affinity (bg = n&7).
// Wave = 4t x 64l x 64d; E/vw wave-uniform -> scalar loads; 8-deep F dbuf.
__global__ __launch_bounds__(64) void k_scoreT(const float* __restrict__ Eg,
                                               const float* __restrict__ imgF4,
                                               const float* __restrict__ vw,
                                               float* __restrict__ g8) {
  const int lane = threadIdx.x;
  int n = blockIdx.x;
  const int bg = n & 7;
  int m = n >> 3;  // 768 = 4 bi * 3 lc * 8 tq * 8 dq
  const int bi = m & 3; m >>= 2;
  const int lc = m % 3; m /= 3;
  const int tq = m & 7;
  const int dq = m >> 3;
  const int b = bg * 4 + bi;
  const int t0 = (tq < 7) ? tq * 4 : 26;  // rows 26,27 dup'd by tq=6/7 (bit-identical)
  const float* Fp =
      imgF4 + (((size_t)(b * 128 + dq * 16)) * kL + lc * 64 + lane) * 4;
  const float* e0 = Eg + ((size_t)(b * kT + t0)) * kD + dq * 64;
  const float* e1 = e0 + kD;
  const float* e2 = e0 + 2 * kD;
  const float* e3 = e0 + 3 * kD;
  const float* vp = vw + dq * 64;
  float a0 = 0.f, a1 = 0.f, a2 = 0.f, a3 = 0.f;
  auto loadF = [&](float4* dst, int bb) {
#pragma unroll
    for (int j = 0; j < 8; ++j)
      dst[j] = *(const float4*)(Fp + (size_t)(bb * 8 + j) * (kL * 4));
  };
  auto compF = [&](const float4* f, int bb) {
#pragma unroll
    for (int j = 0; j < 8; ++j) {
      const int s = bb * 8 + j;
      const float4 vv = *(const float4*)(vp + 4 * s);   // uniform -> s_load
      const float4 E0 = *(const float4*)(e0 + 4 * s);   // uniform -> s_load
      const float4 E1 = *(const float4*)(e1 + 4 * s);
      const float4 E2 = *(const float4*)(e2 + 4 * s);
      const float4 E3 = *(const float4*)(e3 + 4 * s);
      PAIR(E0.x, E0.y, f[j].x, f[j].y, vv.x, vv.y, a0);
      PAIR(E0.z, E0.w, f[j].z, f[j].w, vv.z, vv.w, a0);
      PAIR(E1.x, E1.y, f[j].x, f[j].y, vv.x, vv.y, a1);
      PAIR(E1.z, E1.w, f[j].z, f[j].w, vv.z, vv.w, a1);
      PAIR(E2.x, E2.y, f[j].x, f[j].y, vv.x, vv.y, a2);
      PAIR(E2.z, E2.w, f[j].z, f[j].w, vv.z, vv.w, a2);
      PAIR(E3.x, E3.y, f[j].x, f[j].y, vv.x, vv.y, a3);
      PAIR(E3.z, E3.w, f[j].z, f[j].w, vv.z, vv.w, a3);
    }
  };
  float4 fA[8], fB[8];
  loadF(fA, 0);
  loadF(fB, 1);
  compF(fA, 0);
  compF(fB, 1);
  float* gp =
      g8 + (size_t)dq * kGsz + ((size_t)(b * kT + t0)) * kL + lc * 64 + lane;
  gp[0] = a0;
  gp[kL] = a1;
  gp[2 * kL] = a2;
  gp[3 * kL] = a3;
}

// softmax over l: l<192 from 8 partials; l=192..195 computed inline (512 d)
__global__ __launch_bounds__(512) void k_alpha(const float* __restrict__ g8,
                                               const float* __restrict__ Eg,
                                               const float* __restrict__ img,
                                               const float* __restrict__ vw,
                                               float* __restrict__ alpha) {
  const int qd = blockIdx.x, b = blockIdx.y;
  const int lane = threadIdx.x & 63, wv = threadIdx.x >> 6;
  const int t = qd * 8 + wv;
  if (t >= kT) return;
  // tail: lane = (l4:4, dc:16); each lane sums 32 d for l = 192+l4
  const int l4 = lane & 3, dc = lane >> 2;
  const float* ir = img + ((size_t)(b * kL + 192 + l4)) * kD + dc * 32;
  const float* er = Eg + ((size_t)(b * kT + t)) * kD + dc * 32;
  const float* vr = vw + dc * 32;
  float tg = 0.f;
#pragma unroll
  for (int k = 0; k < 8; ++k) {
    const float4 iv = *(const float4*)(ir + 4 * k);
    const float4 ev = *(const float4*)(er + 4 * k);
    const float4 vv = *(const float4*)(vr + 4 * k);
    PAIR(ev.x, ev.y, __builtin_amdgcn_exp2f(kK * iv.x),
         __builtin_amdgcn_exp2f(kK * iv.y), vv.x, vv.y, tg);
    PAIR(ev.z, ev.w, __builtin_amdgcn_exp2f(kK * iv.z),
         __builtin_amdgcn_exp2f(kK * iv.w), vv.z, vv.w, tg);
  }
#pragma unroll
  for (int mm = 4; mm < 64; mm <<= 1) tg += __shfl_xor(tg, mm, 64);
  const size_t base = ((size_t)(b * kT + t)) * kL;
  float q0 = 0.f, q1 = 0.f, q2 = 0.f;
#pragma unroll
  for (int p = 0; p < 8; ++p) {
    const float* gp = g8 + (size_t)p * kGsz + base;
    q0 += gp[lane];
    q1 += gp[lane + 64];
    q2 += gp[lane + 128];
  }
  q0 *= kK; q1 *= kK; q2 *= kK;
  float q3 = (lane < 4) ? tg * kK : __builtin_inff();
  float m = fminf(fminf(q0, q1), fminf(q2, q3));
#pragma unroll
  for (int mm = 1; mm < 64; mm <<= 1) m = fminf(m, __shfl_xor(m, mm, 64));
  const float e0 = __builtin_amdgcn_exp2f(m - q0);
  const float e1 = __builtin_amdgcn_exp2f(m - q1);
  const float e2 = __builtin_amdgcn_exp2f(m - q2);
  const float e3 = (lane < 4) ? __builtin_amdgcn_exp2f(m - q3) : 0.f;
  float s = e0 + e1 + e2 + e3;
#pragma unroll
  for (int mm = 1; mm < 64; mm <<= 1) s += __shfl_xor(s, mm, 64);
  const float rs = __builtin_amdgcn_rcpf(s);
  float* ab = alpha + base;
  ab[lane] = e0 * rs;
  ab[lane + 64] = e1 * rs;
  ab[lane + 128] = e2 * rs;
  if (lane < 4) ab[lane + 192] = e3 * rs;
}

// context[b][t][d] = sum_l img[b][l][d]*alpha[b][t][l].
// 384 blocks, XCD b-affinity; 4 waves own 49-l quarters; 8-deep img dbuf.
__global__ __launch_bounds__(256) void k_ctx(const float* __restrict__ img,
                                             const float* __restrict__ alpha,
                                             float* __restrict__ out) {
  __shared__ __align__(16) float red[4][5][256];  // 20 KB
  int n = blockIdx.x;
  const int bg = n & 7;
  int m = n >> 3;  // 48 = 4 bi * 6 tg * 2 dh
  const int bi = m & 3; m >>= 2;
  const int tg = m % 6;
  const int dh = m / 6;
  const int b = bg * 4 + bi;
  const int t0 = tg * 5, d0 = dh * 256;
  const int tid = threadIdx.x;
  const int lane = tid & 63;
  const int lru = __builtin_amdgcn_readfirstlane(tid >> 6);
  const float* ap = alpha + ((size_t)(b * kT + t0)) * kL + lru * 49;  // uniform
  const float* ip = img + ((size_t)(b * kL + lru * 49)) * kD + d0 + 4 * lane;
  float4 acc[5];
#pragma unroll
  for (int j = 0; j < 5; ++j) acc[j] = {0.f, 0.f, 0.f, 0.f};
  auto loadI = [&](float4* dst, int bb) {
#pragma unroll
    for (int j = 0; j < 8; ++j)
      dst[j] = *(const float4*)(ip + (size_t)(bb * 8 + j) * kD);
  };
  auto compI = [&](const float4* f, int bb) {
#pragma unroll
    for (int j = 0; j < 8; ++j) {
      const int i = bb * 8 + j;
      const float a0 = ap[i];
      const float a1 = ap[kL + i];
      const float a2 = ap[2 * kL + i];
      const float a3 = ap[3 * kL + i];
      const float a4 = ap[4 * kL + i];
      acc[0].x = fmaf(f[j].x, a0, acc[0].x); acc[0].y = fmaf(f[j].y, a0, acc[0].y);
      acc[0].z = fmaf(f[j].z, a0, acc[0].z); acc[0].w = fmaf(f[j].w, a0, acc[0].w);
      acc[1].x = fmaf(f[j].x, a1, acc[1].x); acc[1].y = fmaf(f[j].y, a1, acc[1].y);
      acc[1].z = fmaf(f[j].z, a1, acc[1].z); acc[1].w = fmaf(f[j].w, a1, acc[1].w);
      acc[2].x = fmaf(f[j].x, a2, acc[2].x); acc[2].y = fmaf(f[j].y, a2, acc[2].y);
      acc[2].z = fmaf(f[j].z, a2, acc[2].z); acc[2].w = fmaf(f[j].w, a2, acc[2].w);
      acc[3].x = fmaf(f[j].x, a3, acc[3].x); acc[3].y = fmaf(f[j].y, a3, acc[3].y);
      acc[3].z = fmaf(f[j].z, a3, acc[3].z); acc[3].w = fmaf(f[j].w, a3, acc[3].w);
      acc[4].x = fmaf(f[j].x, a4, acc[4].x); acc[4].y = fmaf(f[j].y, a4, acc[4].y);
      acc[4].z = fmaf(f[j].z, a4, acc[4].z); acc[4].w = fmaf(f[j].w, a4, acc[4].w);
    }
  };
  float4 fA[8], fB[8];
  loadI(fA, 0);
  loadI(fB, 1); compI(fA, 0);
  loadI(fA, 2); compI(fB, 1);
  loadI(fB, 3); compI(fA, 2);
  loadI(fA, 4); compI(fB, 3);
  loadI(fB, 5); compI(fA, 4);
  compI(fB, 5);
  {  // tail l-index 48 of this quarter
    const float4 v = *(const float4*)(ip + (size_t)48 * kD);
    const int i = 48;
    const float a0 = ap[i], a1 = ap[kL + i], a2 = ap[2 * kL + i],
                a3 = ap[3 * kL + i], a4 = ap[4 * kL + i];
    acc[0].x = fmaf(v.x, a0, acc[0].x); acc[0].y = fmaf(v.y, a0, acc[0].y);
    acc[0].z = fmaf(v.z, a0, acc[0].z); acc[0].w = fmaf(v.w, a0, acc[0].w);
    acc[1].x = fmaf(v.x, a1, acc[1].x); acc[1].y = fmaf(v.y, a1, acc[1].y);
    acc[1].z = fmaf(v.z, a1, acc[1].z); acc[1].w = fmaf(v.w, a1, acc[1].w);
    acc[2].x = fmaf(v.x, a2, acc[2].x); acc[2].y = fmaf(v.y, a2, acc[2].y);
    acc[2].z = fmaf(v.z, a2, acc[2].z); acc[2].w = fmaf(v.w, a2, acc[2].w);
    acc[3].x = fmaf(v.x, a3, acc[3].x); acc[3].y = fmaf(v.y, a3, acc[3].y);
    acc[3].z = fmaf(v.z, a3, acc[3].z); acc[3].w = fmaf(v.w, a3, acc[3].w);
    acc[4].x = fmaf(v.x, a4, acc[4].x); acc[4].y = fmaf(v.y, a4, acc[4].y);
    acc[4].z = fmaf(v.z, a4, acc[4].z); acc[4].w = fmaf(v.w, a4, acc[4].w);
  }
#pragma unroll
  for (int j = 0; j < 5; ++j) *(float4*)&red[lru][j][4 * lane] = acc[j];
  __syncthreads();
#pragma unroll
  for (int j = 0; j < 5; ++j) {
    const float s =
        red[0][j][tid] + red[1][j][tid] + red[2][j][tid] + red[3][j][tid];
    out[((size_t)(b * kT + t0 + j)) * kD + d0 + tid] = s;
  }
}
}  // namespace

extern "C" void kernel_launch(void* const* d_in, const int* in_sizes, int n_in,
                              void* d_out, int out_size, void* d_ws, size_t ws_size,
                              hipStream_t stream) {
  const float* x = (const float*)d_in[0];
  const float* wordemb = (const float*)d_in[1];
  const float* img = (const float*)d_in[2];
  const float* vw = (const float*)d_in[3];
  // v_b (d_in[4]) cancels in the softmax along with sum(v_w) — unused by design.
  float* out = (float*)d_out;
  float* Eg = (float*)d_ws;        // 1.97 MB
  float* imgF4 = Eg + kEgN;        // 12.8 MB
  float* g8 = imgF4 + kFN;         // 6.02 MB
  float* alpha = g8 + 8 * kGsz;    // 0.75 MB
  hipLaunchKernelGGL(k_prep, dim3(568), dim3(256), 0, stream, x, wordemb, img,
                     Eg, imgF4);
  hipLaunchKernelGGL(k_scoreT, dim3(6144), dim3(64), 0, stream, Eg, imgF4, vw,
                     g8);
  hipLaunchKernelGGL(k_alpha, dim3(4, kB), dim3(512), 0, stream, g8, Eg, img,
                     vw, alpha);
  hipLaunchKernelGGL(k_ctx, dim3(384), dim3(256), 0, stream, img, alpha, out);
}